// Round 9
// baseline (467.895 us; speedup 1.0000x reference)
//
#include <hip/hip_runtime.h>
#include <hip/hip_bf16.h>

// ResidualVQVAE forward, FP32 in / FP32 out.
// R17: argmin inner engine rebuilt on mfma_f32_32x32x16_bf16 (128 MFMAs/wave vs 256,
// -17% matrix-pipe, half the issue slots) with codebook pre-swizzled to the 32x32
// B-frag layout; staging via __builtin_amdgcn_global_load_lds width=16 (no staging
// VGPRs/VALU; pre-barrier vmcnt drain is the sync). Grid/tiling/scan-order/tie-breaks
// unchanged -> identical picks. Rest = R16-proven pipeline. 18 dispatches.

typedef __bf16 bf16x8 __attribute__((ext_vector_type(8)));
typedef float  f32x4  __attribute__((ext_vector_type(4)));
typedef float  f32x16 __attribute__((ext_vector_type(16)));
typedef unsigned short ushort8v __attribute__((ext_vector_type(8)));

#define MFMA16(a,b,c) __builtin_amdgcn_mfma_f32_16x16x32_bf16((a),(b),(c),0,0,0)
#define MFMA32(a,b,c) __builtin_amdgcn_mfma_f32_32x32x16_bf16((a),(b),(c),0,0,0)

__device__ __forceinline__ float b2f(ushort u){ return __uint_as_float(((unsigned)u) << 16); }
__device__ __forceinline__ ushort f2b_rne(float x){
  unsigned u = __float_as_uint(x);
  return (ushort)((u + 0x7fffu + ((u >> 16) & 1u)) >> 16);
}

__device__ __forceinline__ void gload_lds16(const void* g, void* l){
  __builtin_amdgcn_global_load_lds(
      (const __attribute__((address_space(1))) unsigned int*)g,
      (__attribute__((address_space(3))) unsigned int*)l, 16, 0, 0);
}

__device__ __forceinline__ void cvt8(const float* p, bf16x8& h8, bf16x8& l8){
  f32x4 v0 = *(const f32x4*)p;
  f32x4 v1 = *(const f32x4*)(p + 4);
  ushort8v uh, ul;
  #pragma unroll
  for (int i = 0; i < 4; i++){
    float a = v0[i]; ushort h = f2b_rne(a); uh[i] = h;     ul[i]     = f2b_rne(a - b2f(h));
    float b = v1[i]; ushort g = f2b_rne(b); uh[i + 4] = g; ul[i + 4] = f2b_rne(b - b2f(g));
  }
  h8 = __builtin_bit_cast(bf16x8, uh);
  l8 = __builtin_bit_cast(bf16x8, ul);
}

template<int KK, int NN, bool HAS_BLO>
__device__ __forceinline__ f32x4 dotct(const bf16x8* ah, const bf16x8* al,
                                       const ushort* __restrict__ Bfh,
                                       const ushort* __restrict__ Bfl,
                                       int ct, int L){
  constexpr int KS = KK / 32, CT = NN / 16;
  f32x4 acc = {0.f, 0.f, 0.f, 0.f};
  #pragma unroll
  for (int ks = 0; ks < KS; ks++){
    int bo = ((ks * CT + ct) * 64 + L) * 8;
    bf16x8 bh = *(const bf16x8*)(Bfh + bo);
    acc = MFMA16(ah[ks], bh, acc);
    acc = MFMA16(al[ks], bh, acc);
    if constexpr (HAS_BLO){
      bf16x8 bl = *(const bf16x8*)(Bfl + bo);
      acc = MFMA16(ah[ks], bl, acc);
    }
  }
  return acc;
}

// ---------------- per-book: codebook -> bf16 32x32-MFMA B-frag layout + half-norms --------
// For code c, dim d: group g=c>>5 (32 codes), ks=d>>4 (K-slice of 16), khalf=(d>>3)&1,
// t=d&7, col=c&31. Frag elem = lane(khalf*32+col)*8 + t.
__device__ __forceinline__ void ebook_body(const float* __restrict__ Ef, ushort* __restrict__ Eb,
                                           float* __restrict__ hen, int code, int L){
  float2 e2 = *(const float2*)(Ef + code * 128 + L * 2);
  ushort h0 = f2b_rne(e2.x), h1 = f2b_rne(e2.y);
  int d = L * 2;
  int o = ((code >> 5) * 8 + (d >> 4)) * 512 + ((d >> 3) & 1) * 256 + (code & 31) * 8 + (d & 7);
  *(unsigned*)(Eb + o) = (unsigned)h0 | ((unsigned)h1 << 16);
  float eh0 = b2f(h0), eh1 = b2f(h1);
  float s = eh0 * eh0 + eh1 * eh1;
  #pragma unroll
  for (int mask = 1; mask <= 32; mask <<= 1) s += __shfl_xor(s, mask);
  if (L == 0) hen[code] = 0.5f * s;
}

// ---------------- prep: weight swizzle + BN fold + ebook(book 0) --------------------------
__device__ __forceinline__ void swz_body(const float* __restrict__ Wm, ushort* __restrict__ Wfh,
                                         ushort* __restrict__ Wfl, int N, int b){
  int gid = b * 256 + threadIdx.x;
  int k = gid / N, n = gid - k * N;
  int kt = k >> 5, kr = k & 31, nt = n >> 4, nr = n & 15;
  int lane = (kr >> 3) * 16 + nr, tt = kr & 7;
  int o = (((kt * (N >> 4)) + nt) * 64 + lane) * 8 + tt;
  float v = Wm[gid];
  ushort h = f2b_rne(v);
  Wfh[o] = h;
  if (Wfl) Wfl[o] = f2b_rne(v - b2f(h));
}

__global__ __launch_bounds__(256) void k_prep(
    const float* __restrict__ W1, const float* __restrict__ W2, const float* __restrict__ W3,
    const float* __restrict__ W4, const float* __restrict__ W5, const float* __restrict__ W6,
    ushort* W1fh, ushort* W1fl, ushort* W2fh, ushort* W2fl, ushort* W3fh, ushort* W3fl,
    ushort* W4fh, ushort* W5fh, ushort* W6fh,
    const float* __restrict__ CB, ushort* __restrict__ Eb, float* __restrict__ hen,
    const float* g1,const float* be1,const float* rm1,const float* rv1,
    const float* g2,const float* be2,const float* rm2,const float* rv2,
    const float* g3,const float* be3,const float* rm3,const float* rv3,
    const float* g4,const float* be4,const float* rm4,const float* rv4,
    float* s1,float* t1,float* s2,float* t2,float* s3,float* t3,float* s4,float* t4)
{
  int b = blockIdx.x;
  if (b < 768){
    if      (b < 128) swz_body(W1, W1fh, W1fl, 128, b);
    else if (b < 256) swz_body(W2, W2fh, W2fl, 256, b - 128);
    else if (b < 384) swz_body(W3, W3fh, W3fl, 128, b - 256);
    else if (b < 512) swz_body(W4, W4fh, nullptr, 256, b - 384);
    else if (b < 640) swz_body(W5, W5fh, nullptr, 128, b - 512);
    else              swz_body(W6, W6fh, nullptr, 256, b - 640);
  } else if (b == 768){
    int t = threadIdx.x;
    if (t < 128){
      float sa = g1[t] / sqrtf(rv1[t] + 1e-5f);
      s1[t] = sa; t1[t] = be1[t] - rm1[t] * sa;
      float sb = g4[t] / sqrtf(rv4[t] + 1e-5f);
      s4[t] = sb; t4[t] = be4[t] - rm4[t] * sb;
    }
    if (t < 256){
      float sa = g2[t] / sqrtf(rv2[t] + 1e-5f);
      s2[t] = sa; t2[t] = be2[t] - rm2[t] * sa;
      float sb = g3[t] / sqrtf(rv3[t] + 1e-5f);
      s3[t] = sb; t3[t] = be3[t] - rm3[t] * sb;
    }
  } else {
    // ebook for book 0: blocks 769..2816, 4 codes/block
    ebook_body(CB, Eb, hen, (b - 769) * 4 + (threadIdx.x >> 6), threadIdx.x & 63);
  }
}

// ---------------- fused encoder -----------------------------------------------------------
__global__ __launch_bounds__(256) void k_encoder(
    const float* __restrict__ x,
    const ushort* __restrict__ W1fh, const ushort* __restrict__ W1fl,
    const ushort* __restrict__ W2fh, const ushort* __restrict__ W2fl,
    const ushort* __restrict__ W3fh, const ushort* __restrict__ W3fl,
    const float* __restrict__ b1, const float* __restrict__ s1, const float* __restrict__ t1,
    const float* __restrict__ b2, const float* __restrict__ s2, const float* __restrict__ t2,
    const float* __restrict__ b3,
    ushort* __restrict__ rhi, float* __restrict__ res)
{
  __shared__ __align__(16) float sA[16 * 260];
  __shared__ __align__(16) float sB[16 * 132];
  int tid = threadIdx.x;
  int wv = tid >> 6, L = tid & 63;
  int qd = L >> 4, c16 = L & 15;
  int row0 = blockIdx.x * 16;

  bf16x8 a1h[8], a1l[8];
  #pragma unroll
  for (int ks = 0; ks < 8; ks++)
    cvt8(x + (row0 + c16) * 256 + ks * 32 + qd * 8, a1h[ks], a1l[ks]);

  #pragma unroll
  for (int u = 0; u < 2; u++){
    int ct = wv * 2 + u;
    f32x4 acc = dotct<256,128,true>(a1h, a1l, W1fh, W1fl, ct, L);
    int col = ct * 16 + c16;
    float bia = b1[col], sc = s1[col], sh = t1[col];
    #pragma unroll
    for (int i = 0; i < 4; i++){
      float v = (acc[i] + bia) * sc + sh;
      sB[(qd * 4 + i) * 132 + col] = fmaxf(v, 0.f);
    }
  }
  __syncthreads();

  bf16x8 a2h[4], a2l[4];
  #pragma unroll
  for (int ks = 0; ks < 4; ks++)
    cvt8(sB + c16 * 132 + ks * 32 + qd * 8, a2h[ks], a2l[ks]);

  #pragma unroll
  for (int u = 0; u < 4; u++){
    int ct = wv * 4 + u;
    f32x4 acc = dotct<128,256,true>(a2h, a2l, W2fh, W2fl, ct, L);
    int col = ct * 16 + c16;
    float bia = b2[col], sc = s2[col], sh = t2[col];
    #pragma unroll
    for (int i = 0; i < 4; i++){
      float v = (acc[i] + bia) * sc + sh;
      sA[(qd * 4 + i) * 260 + col] = fmaxf(v, 0.f);
    }
  }
  __syncthreads();

  bf16x8 a3h[8], a3l[8];
  #pragma unroll
  for (int ks = 0; ks < 8; ks++)
    cvt8(sA + c16 * 260 + ks * 32 + qd * 8, a3h[ks], a3l[ks]);

  #pragma unroll
  for (int u = 0; u < 2; u++){
    int ct = wv * 2 + u;
    f32x4 acc = dotct<256,128,true>(a3h, a3l, W3fh, W3fl, ct, L);
    int col = ct * 16 + c16;
    float bia = b3[col];
    #pragma unroll
    for (int i = 0; i < 4; i++){
      int row = row0 + qd * 4 + i;
      float v = acc[i] + bia;
      int o = row * 128 + col;
      res[o] = v;
      rhi[o] = f2b_rne(v);
    }
  }
}

// ---------------- fused decoder -----------------------------------------------------------
__global__ __launch_bounds__(256) void k_decoder(
    const ushort* __restrict__ dhi, const ushort* __restrict__ dlo,
    const ushort* __restrict__ W4fh, const ushort* __restrict__ W5fh,
    const ushort* __restrict__ W6fh,
    const float* __restrict__ b4, const float* __restrict__ s3, const float* __restrict__ t3,
    const float* __restrict__ b5, const float* __restrict__ s4, const float* __restrict__ t4,
    const float* __restrict__ b6,
    float* __restrict__ xhat)
{
  __shared__ __align__(16) float sA[16 * 260];
  __shared__ __align__(16) float sB[16 * 132];
  int tid = threadIdx.x;
  int wv = tid >> 6, L = tid & 63;
  int qd = L >> 4, c16 = L & 15;
  int row0 = blockIdx.x * 16;

  bf16x8 a1h[4], a1l[4];
  #pragma unroll
  for (int ks = 0; ks < 4; ks++){
    int off = (row0 + c16) * 128 + ks * 32 + qd * 8;
    a1h[ks] = *(const bf16x8*)(dhi + off);
    a1l[ks] = *(const bf16x8*)(dlo + off);
  }

  #pragma unroll
  for (int u = 0; u < 4; u++){
    int ct = wv * 4 + u;
    f32x4 acc = dotct<128,256,false>(a1h, a1l, W4fh, nullptr, ct, L);
    int col = ct * 16 + c16;
    float bia = b4[col], sc = s3[col], sh = t3[col];
    #pragma unroll
    for (int i = 0; i < 4; i++){
      float v = (acc[i] + bia) * sc + sh;
      sA[(qd * 4 + i) * 260 + col] = fmaxf(v, 0.f);
    }
  }
  __syncthreads();

  bf16x8 a2h[8], a2l[8];
  #pragma unroll
  for (int ks = 0; ks < 8; ks++)
    cvt8(sA + c16 * 260 + ks * 32 + qd * 8, a2h[ks], a2l[ks]);

  #pragma unroll
  for (int u = 0; u < 2; u++){
    int ct = wv * 2 + u;
    f32x4 acc = dotct<256,128,false>(a2h, a2l, W5fh, nullptr, ct, L);
    int col = ct * 16 + c16;
    float bia = b5[col], sc = s4[col], sh = t4[col];
    #pragma unroll
    for (int i = 0; i < 4; i++){
      float v = (acc[i] + bia) * sc + sh;
      sB[(qd * 4 + i) * 132 + col] = fmaxf(v, 0.f);
    }
  }
  __syncthreads();

  bf16x8 a3h[4], a3l[4];
  #pragma unroll
  for (int ks = 0; ks < 4; ks++)
    cvt8(sB + c16 * 132 + ks * 32 + qd * 8, a3h[ks], a3l[ks]);

  #pragma unroll
  for (int u = 0; u < 4; u++){
    int ct = wv * 4 + u;
    f32x4 acc = dotct<128,256,false>(a3h, a3l, W6fh, nullptr, ct, L);
    int col = ct * 16 + c16;
    float bia = b6[col];
    #pragma unroll
    for (int i = 0; i < 4; i++)
      xhat[(row0 + qd * 4 + i) * 256 + col] = acc[i] + bia;
  }
}

// ---------------- VQ: hi-only argmax(r.e - 0.5||e||^2), 32x32 MFMA + global_load_lds ------
// grid: 64 row-blocks (128 rows) x 16 chunks (512 codes) = 1024 = 4 blocks/CU exact.
// Per wave: 32 rows resident (A, 32x32 frag layout); per tile (64 codes = 2 groups of
// 32): issue 4 global_load_lds(16B) for next tile -> per group: 8 ds_read_b128 +
// 8x mfma_32x32x16 (one 8-deep K-chain into 16-reg acc init'd to -h) + 16 compares
// -> barrier (compiler's vmcnt drain completes the async stage). ~115 VGPR, 34 KB LDS.
// Ascending-j scan + strict > + smaller-j-on-tie => picks identical to R16.
__global__ __launch_bounds__(256, 4) void k_vq_argmin(
  const ushort* __restrict__ Rhi,
  const ushort* __restrict__ Eb, const float* __restrict__ hen,
  float* __restrict__ cq, int* __restrict__ cj)
{
  __shared__ __align__(16) ushort etile[2][8192];   // 2 x 16 KB
  __shared__ float henl[512];
  int rb = blockIdx.x & 63, ch = blockIdx.x >> 6;
  int tid = threadIdx.x;
  int wv = tid >> 6, L = tid & 63;
  int c32 = L & 31, lh = L >> 5;
  int row0 = rb * 128 + wv * 32;

  // resident A: 32 rows hi-only, 32x32x16 frag layout (row=c32, k=ks*16+lh*8)
  bf16x8 ah[8];
  #pragma unroll
  for (int ks = 0; ks < 8; ks++)
    ah[ks] = *(const bf16x8*)(Rhi + (row0 + c32) * 128 + ks * 16 + lh * 8);

  henl[tid] = hen[ch * 512 + tid];
  henl[tid + 256] = hen[ch * 512 + 256 + tid];

  float best[16]; int bj[16];
  #pragma unroll
  for (int i = 0; i < 16; i++){ best[i] = -3.0e38f; bj[i] = 0; }

  const ushort* ebc = Eb + (size_t)ch * 65536;      // chunk base (512 codes, frag layout)
  int jb = ch * 512 + c32;

  // stage tile 0 (async direct-to-LDS)
  #pragma unroll
  for (int j = 0; j < 4; j++)
    gload_lds16(ebc + j * 2048 + wv * 512 + L * 8, etile[0] + j * 4096 + wv * 512);
  __syncthreads();

  #pragma unroll 1
  for (int tile = 0; tile < 8; ++tile){
    int cur = tile & 1;
    if (tile < 7){
      const ushort* src = ebc + (size_t)(tile + 1) * 8192;
      ushort* nb = etile[cur ^ 1];
      #pragma unroll
      for (int j = 0; j < 4; j++)
        gload_lds16(src + j * 2048 + wv * 512 + L * 8, nb + j * 4096 + wv * 512);
    }
    const ushort* lb = etile[cur];
    #pragma unroll
    for (int g = 0; g < 2; ++g){
      const ushort* gp = lb + g * 4096 + L * 8;
      int gg = tile * 2 + g;
      float mh = -henl[gg * 32 + c32];
      f32x16 acc;
      #pragma unroll
      for (int i = 0; i < 16; i++) acc[i] = mh;
      bf16x8 b0 = *(const bf16x8*)(gp + 0);
      bf16x8 b1 = *(const bf16x8*)(gp + 512);
      bf16x8 b2 = *(const bf16x8*)(gp + 1024);
      bf16x8 b3 = *(const bf16x8*)(gp + 1536);
      __builtin_amdgcn_s_setprio(1);
      acc = MFMA32(ah[0], b0, acc);
      acc = MFMA32(ah[1], b1, acc);
      acc = MFMA32(ah[2], b2, acc);
      acc = MFMA32(ah[3], b3, acc);
      __builtin_amdgcn_s_setprio(0);
      bf16x8 b4 = *(const bf16x8*)(gp + 2048);
      bf16x8 b5 = *(const bf16x8*)(gp + 2560);
      bf16x8 b6 = *(const bf16x8*)(gp + 3072);
      bf16x8 b7 = *(const bf16x8*)(gp + 3584);
      __builtin_amdgcn_s_setprio(1);
      acc = MFMA32(ah[4], b4, acc);
      acc = MFMA32(ah[5], b5, acc);
      acc = MFMA32(ah[6], b6, acc);
      acc = MFMA32(ah[7], b7, acc);
      __builtin_amdgcn_s_setprio(0);
      int jc = jb + gg * 32;
      #pragma unroll
      for (int i = 0; i < 16; i++)
        if (acc[i] > best[i]){ best[i] = acc[i]; bj[i] = jc; }
    }
    __syncthreads();
  }

  // cross-lane reduce over the 32 code-columns, ties -> smaller j
  #pragma unroll
  for (int mask = 1; mask <= 16; mask <<= 1){
    #pragma unroll
    for (int i = 0; i < 16; i++){
      float ob = __shfl_xor(best[i], mask);
      int   oj = __shfl_xor(bj[i], mask);
      if (ob > best[i] || (ob == best[i] && oj < bj[i])){ best[i] = ob; bj[i] = oj; }
    }
  }
  if (c32 == 0){
    #pragma unroll
    for (int i = 0; i < 16; i++){
      int r = row0 + (i & 3) + 8 * (i >> 2) + 4 * lh;   // 32x32 C-layout row
      cq[r * 16 + ch] = best[i];
      cj[r * 16 + ch] = bj[i];
    }
  }
}

// ---------------- VQ: combine 16 chunk candidates, emit res_s/ce_s, update, + next ebook --
template<bool LAST>
__global__ __launch_bounds__(256) void k_vq_update(
  const float* __restrict__ cq, const int* __restrict__ cj,
  const float* __restrict__ Ef, const float* __restrict__ Efn,
  ushort* __restrict__ Eb, float* __restrict__ hen,
  float* __restrict__ res, const float* __restrict__ ze_s,
  ushort* __restrict__ rhi, ushort* __restrict__ rlo,
  float* __restrict__ res_s, float* __restrict__ ce_s)
{
  int idx = blockIdx.x * 4 + (threadIdx.x >> 6);
  int L = threadIdx.x & 63;
  int c = L & 15;
  float bq = cq[idx * 16 + c]; int bi = cj[idx * 16 + c];
  #pragma unroll
  for (int mask = 1; mask <= 8; mask <<= 1){
    float ob = __shfl_xor(bq, mask);
    int   oj = __shfl_xor(bi, mask);
    if (ob > bq || (ob == bq && oj < bi)){ bq = ob; bi = oj; }
  }
  int o = idx * 128 + L * 2;
  float2 ce = *(const float2*)(Ef + bi * 128 + L * 2);   // fp32 codebook row
  float2 r2 = *(const float2*)(res + o);
  *(float2*)(res_s + o) = r2;
  *(float2*)(ce_s + o) = ce;
  float rn0 = r2.x - ce.x, rn1 = r2.y - ce.y;
  if constexpr (LAST){
    float2 z2 = *(const float2*)(ze_s + o);              // ze from res_s[0]
    float d0 = z2.x - rn0, d1 = z2.y - rn1;              // di = ze - res_final
    ushort h0 = f2b_rne(d0), h1 = f2b_rne(d1);
    *(unsigned*)(rhi + o) = (unsigned)h0 | ((unsigned)h1 << 16);
    ushort l0 = f2b_rne(d0 - b2f(h0)), l1 = f2b_rne(d1 - b2f(h1));
    *(unsigned*)(rlo + o) = (unsigned)l0 | ((unsigned)l1 << 16);
  } else {
    res[o] = rn0; res[o + 1] = rn1;
    ushort h0 = f2b_rne(rn0), h1 = f2b_rne(rn1);
    *(unsigned*)(rhi + o) = (unsigned)h0 | ((unsigned)h1 << 16);
    ebook_body(Efn, Eb, hen, idx, L);
  }
}

extern "C" void kernel_launch(void* const* d_in, const int* in_sizes, int n_in,
                              void* d_out, int out_size, void* d_ws, size_t ws_size,
                              hipStream_t stream)
{
  const float* x   = (const float*)d_in[0];
  const float* W1  = (const float*)d_in[1];
  const float* b1  = (const float*)d_in[2];
  const float* g1  = (const float*)d_in[3];
  const float* be1 = (const float*)d_in[4];
  const float* rm1 = (const float*)d_in[5];
  const float* rv1 = (const float*)d_in[6];
  const float* W2  = (const float*)d_in[7];
  const float* b2  = (const float*)d_in[8];
  const float* g2  = (const float*)d_in[9];
  const float* be2 = (const float*)d_in[10];
  const float* rm2 = (const float*)d_in[11];
  const float* rv2 = (const float*)d_in[12];
  const float* W3  = (const float*)d_in[13];
  const float* b3  = (const float*)d_in[14];
  const float* CB  = (const float*)d_in[15];
  const float* W4  = (const float*)d_in[16];
  const float* b4  = (const float*)d_in[17];
  const float* g3  = (const float*)d_in[18];
  const float* be3 = (const float*)d_in[19];
  const float* rm3 = (const float*)d_in[20];
  const float* rv3 = (const float*)d_in[21];
  const float* W5  = (const float*)d_in[22];
  const float* b5  = (const float*)d_in[23];
  const float* g4  = (const float*)d_in[24];
  const float* be4 = (const float*)d_in[25];
  const float* rm4 = (const float*)d_in[26];
  const float* rv4 = (const float*)d_in[27];
  const float* W6  = (const float*)d_in[28];
  const float* b6  = (const float*)d_in[29];

  char* w = (char*)d_ws;
  ushort* Eb   = (ushort*)(w + 0);             // per-book bf16 codebook (frag layout), 2 MiB
  float*  cq   = (float*) (w + 2097152);       // 8192x16, 512 KiB
  int*    cj   = (int*)   (w + 2621440);       // 8192x16, 512 KiB
  ushort* rhi  = (ushort*)(w + 12582912);      // residual hi split, 2 MiB
  ushort* rlo  = (ushort*)(w + 14680064);      // decoder dlo, 2 MiB
  float*  res  = (float*) (w + 16777216);      // 4 MiB
  float*  hen  = (float*) (w + 25165824);      // per-book half-norms, 32 KiB
  float*  s1   = (float*) (w + 25198592);
  float*  t1   = (float*) (w + 25199104);
  float*  s2   = (float*) (w + 25199616);
  float*  t2   = (float*) (w + 25200640);
  float*  s3   = (float*) (w + 25201664);
  float*  t3   = (float*) (w + 25202688);
  float*  s4   = (float*) (w + 25203712);
  float*  t4   = (float*) (w + 25204224);
  ushort* W1fh = (ushort*)(w + 25204736);
  ushort* W2fh = (ushort*)(w + 25270272);
  ushort* W3fh = (ushort*)(w + 25335808);
  ushort* W4fh = (ushort*)(w + 25401344);
  ushort* W5fh = (ushort*)(w + 25466880);
  ushort* W6fh = (ushort*)(w + 25532416);
  ushort* W1fl = (ushort*)(w + 25597952);
  ushort* W2fl = (ushort*)(w + 25663488);
  ushort* W3fl = (ushort*)(w + 25729024);

  float* xhat  = (float*)d_out;                // [8192,256] fp32
  float* res_s = xhat + 2097152;               // [8,8192,128] fp32
  float* ce_s  = res_s + 8388608;              // [8,8192,128] fp32

  // prep: weights + BN fold + ebook(book 0)
  k_prep<<<2817, 256, 0, stream>>>(W1, W2, W3, W4, W5, W6,
                                   W1fh, W1fl, W2fh, W2fl, W3fh, W3fl,
                                   W4fh, W5fh, W6fh,
                                   CB, Eb, hen,
                                   g1,be1,rm1,rv1, g2,be2,rm2,rv2,
                                   g3,be3,rm3,rv3, g4,be4,rm4,rv4,
                                   s1,t1,s2,t2,s3,t3,s4,t4);

  k_encoder<<<512, 256, 0, stream>>>(x, W1fh, W1fl, W2fh, W2fl, W3fh, W3fl,
                                     b1, s1, t1, b2, s2, t2, b3,
                                     rhi, res);

  // residual VQ over 8 books (ebook for book m+1 fused into update(m))
  for (int m = 0; m < 8; m++){
    const float* Ef = CB + (size_t)m * 1048576;
    k_vq_argmin<<<1024, 256, 0, stream>>>(rhi, Eb, hen, cq, cj);
    if (m < 7){
      k_vq_update<false><<<2048, 256, 0, stream>>>(cq, cj, Ef, Ef + 1048576, Eb, hen,
                                                   res, nullptr, rhi, nullptr,
                                                   res_s + (size_t)m * 1048576,
                                                   ce_s  + (size_t)m * 1048576);
    } else {
      k_vq_update<true><<<2048, 256, 0, stream>>>(cq, cj, Ef, nullptr, Eb, hen,
                                                  res, res_s /*ze = res_s[0]*/, rhi, rlo,
                                                  res_s + (size_t)m * 1048576,
                                                  ce_s  + (size_t)m * 1048576);
    }
  }

  // fused decoder (rhi/rlo hold split(di) from update<LAST>)
  k_decoder<<<512, 256, 0, stream>>>(rhi, rlo, W4fh, W5fh, W6fh,
                                     b4, s3, t3, b5, s4, t4, b6, xhat);
}